// Round 1
// 200.575 us; speedup vs baseline: 1.3256x; 1.3256x over previous
//
#include <hip/hip_runtime.h>

#define B_ 4
#define N_ 16384
#define D_ 64
#define H_ 8
#define E_ 512
#define NCHUNK 24
#define NTILES (N_ / 64)

typedef __attribute__((ext_vector_type(8))) short short8;
typedef __attribute__((ext_vector_type(4))) float f32x4;

// f32 -> bf16 (RNE)
__device__ __forceinline__ unsigned short f2b(float f) {
    unsigned u = __float_as_uint(f);
    return (unsigned short)((u + 0x7fffu + ((u >> 16) & 1u)) >> 16);
}

// ---------------------------------------------------------------------------
// k_init: zero kv_sum (B*H*4096 f32)
// ---------------------------------------------------------------------------
__global__ __launch_bounds__(256) void k_init(float* kv_sum)
{
    kv_sum[blockIdx.x * 256 + threadIdx.x] = 0.f;
}

// ---------------------------------------------------------------------------
// k_wqt: WqT[e][kin] = bf16(Wq[kin][e])   (e = h*64+feat, 512x64 bf16 = 64 KB)
// One-time transpose so k_out can load B-fragments straight from global.
// ---------------------------------------------------------------------------
__global__ __launch_bounds__(256) void k_wqt(const float* __restrict__ Wq,
                                             unsigned short* __restrict__ WqT)
{
    int id = blockIdx.x * 256 + threadIdx.x;   // 32768 total
    int e = id >> 6, kin = id & 63;
    WqT[id] = f2b(Wq[(size_t)kin * E_ + e]);
}

// ---------------------------------------------------------------------------
// Kernel 1 (MFMA): k,v projection + LN + RoPE(k) + kv accumulation.
// grid (NCHUNK, H, B), 256 thr = 4 waves. mfma_f32_16x16x32_bf16.
// Layouts (verified): A[m=lane&15][k=quad*8+j]; D col=lane&15,row=quad*4+reg.
// LDS rows stride 72 u16 = 144 B (16B-aligned for b128 frag loads).
// ---------------------------------------------------------------------------
__global__ __launch_bounds__(256, 3) void k_kv(
    const float* __restrict__ x,
    const float* __restrict__ pos,
    const float* __restrict__ Wk,
    const float* __restrict__ Wv,
    float* __restrict__ kv_sum)
{
    const int b = blockIdx.z, h = blockIdx.y, chunk = blockIdx.x;
    const int tid  = threadIdx.x;
    const int lane = tid & 63;
    const int w    = tid >> 6;        // wave id 0..3
    const int c    = lane & 15;
    const int quad = lane >> 4;
    const int m0   = w * 16;          // wave's 16-row band (tokens in proj, feats in kv)

    __shared__ unsigned short xbuf[64 * 72];   // x tile bf16 [tok][kin]
    __shared__ unsigned short wkb[64 * 72];    // Wk^T bf16 [feat][kin]
    __shared__ unsigned short wvb[64 * 72];    // Wv^T bf16 [feat][kin]
    __shared__ unsigned short kbuf[64 * 72];   // k bf16 [feat][tok]
    __shared__ unsigned short vbuf[64 * 72];   // v bf16 [feat][tok]
    __shared__ float posb[64];

    // Stage W transposed (once per block, amortized over ~11 tiles)
    for (int i = tid; i < 1024; i += 256) {
        int kin = i >> 4, c4 = (i & 15) * 4;
        float4 wk4 = *(const float4*)&Wk[(size_t)kin * E_ + h * 64 + c4];
        float4 wv4 = *(const float4*)&Wv[(size_t)kin * E_ + h * 64 + c4];
        wkb[(c4 + 0) * 72 + kin] = f2b(wk4.x);
        wkb[(c4 + 1) * 72 + kin] = f2b(wk4.y);
        wkb[(c4 + 2) * 72 + kin] = f2b(wk4.z);
        wkb[(c4 + 3) * 72 + kin] = f2b(wk4.w);
        wvb[(c4 + 0) * 72 + kin] = f2b(wv4.x);
        wvb[(c4 + 1) * 72 + kin] = f2b(wv4.y);
        wvb[(c4 + 2) * 72 + kin] = f2b(wv4.z);
        wvb[(c4 + 3) * 72 + kin] = f2b(wv4.w);
    }

    const float invf_lo = exp2f(-0.4152410118609203f * (float)c);  // 10000^(-c/32)
    const float invf_hi = invf_lo * 0.01f;                          // 10000^(-(16+c)/32)

    f32x4 akv[4];
    #pragma unroll
    for (int nt = 0; nt < 4; ++nt) akv[nt] = (f32x4){0.f, 0.f, 0.f, 0.f};

    for (int tile = chunk; tile < NTILES; tile += NCHUNK) {
        const int n0 = tile * 64;

        // ---- stage x tile (bf16) + pos ----
        for (int i = tid; i < 1024; i += 256) {
            int r = i >> 4, c4 = (i & 15) * 4;
            float4 v = *(const float4*)&x[(size_t)(b * N_ + n0 + r) * 64 + c4];
            ushort4 u;
            u.x = f2b(v.x); u.y = f2b(v.y); u.z = f2b(v.z); u.w = f2b(v.w);
            *(ushort4*)&xbuf[r * 72 + c4] = u;
        }
        if (tid < 64) posb[tid] = pos[(size_t)b * N_ + n0 + tid] * 64.0f;
        __syncthreads();

        // ---- proj: tokens m0..m0+15 x feats 0..63, K=64 (2 steps) ----
        short8 a0 = *(const short8*)&xbuf[(m0 + c) * 72 + quad * 8];
        short8 a1 = *(const short8*)&xbuf[(m0 + c) * 72 + 32 + quad * 8];
        f32x4 ak[4], av[4];
        #pragma unroll
        for (int nt = 0; nt < 4; ++nt) {
            short8 bk0 = *(const short8*)&wkb[(nt * 16 + c) * 72 + quad * 8];
            short8 bk1 = *(const short8*)&wkb[(nt * 16 + c) * 72 + 32 + quad * 8];
            f32x4 z = {0.f, 0.f, 0.f, 0.f};
            z = __builtin_amdgcn_mfma_f32_16x16x32_bf16(a0, bk0, z, 0, 0, 0);
            ak[nt] = __builtin_amdgcn_mfma_f32_16x16x32_bf16(a1, bk1, z, 0, 0, 0);
            short8 bv0 = *(const short8*)&wvb[(nt * 16 + c) * 72 + quad * 8];
            short8 bv1 = *(const short8*)&wvb[(nt * 16 + c) * 72 + 32 + quad * 8];
            f32x4 y = {0.f, 0.f, 0.f, 0.f};
            y = __builtin_amdgcn_mfma_f32_16x16x32_bf16(a0, bv0, y, 0, 0, 0);
            av[nt] = __builtin_amdgcn_mfma_f32_16x16x32_bf16(a1, bv1, y, 0, 0, 0);
        }

        // ---- LN per token (row = quad*4+r; feats spread over nt x 16 lanes) ----
        float kn[4][4], vn[4][4];   // [nt][r]
        #pragma unroll
        for (int r = 0; r < 4; ++r) {
            float sk  = ak[0][r] + ak[1][r] + ak[2][r] + ak[3][r];
            float sk2 = ak[0][r]*ak[0][r] + ak[1][r]*ak[1][r] + ak[2][r]*ak[2][r] + ak[3][r]*ak[3][r];
            float sv  = av[0][r] + av[1][r] + av[2][r] + av[3][r];
            float sv2 = av[0][r]*av[0][r] + av[1][r]*av[1][r] + av[2][r]*av[2][r] + av[3][r]*av[3][r];
            #pragma unroll
            for (int msk = 1; msk < 16; msk <<= 1) {
                sk  += __shfl_xor(sk,  msk, 64);
                sk2 += __shfl_xor(sk2, msk, 64);
                sv  += __shfl_xor(sv,  msk, 64);
                sv2 += __shfl_xor(sv2, msk, 64);
            }
            float mk = sk * (1.0f / 64.0f);
            float rk = rsqrtf(sk2 * (1.0f / 64.0f) - mk * mk + 1e-5f);
            float mv = sv * (1.0f / 64.0f);
            float rv = rsqrtf(sv2 * (1.0f / 64.0f) - mv * mv + 1e-5f);
            #pragma unroll
            for (int nt = 0; nt < 4; ++nt) {
                kn[nt][r] = (ak[nt][r] - mk) * rk;
                vn[nt][r] = (av[nt][r] - mv) * rv;
            }
        }

        // ---- RoPE(k): feat=16nt+c; partner feat^32 = tile nt^2, same lane ----
        #pragma unroll
        for (int r = 0; r < 4; ++r) {
            float tp = posb[m0 + quad * 4 + r];
            float al = tp * invf_lo, ah = tp * invf_hi;
            float cl = __cosf(al), sl = __sinf(al);
            float ch = __cosf(ah), sh = __sinf(ah);
            float lo0 = kn[0][r], hi0 = kn[2][r];
            kn[0][r] = lo0 * cl - hi0 * sl;
            kn[2][r] = hi0 * cl + lo0 * sl;
            float lo1 = kn[1][r], hi1 = kn[3][r];
            kn[1][r] = lo1 * ch - hi1 * sh;
            kn[3][r] = hi1 * ch + lo1 * sh;
        }

        // ---- pack bf16, store transposed [feat][tok] ----
        #pragma unroll
        for (int nt = 0; nt < 4; ++nt) {
            ushort4 pk, pv;
            pk.x = f2b(kn[nt][0]); pk.y = f2b(kn[nt][1]); pk.z = f2b(kn[nt][2]); pk.w = f2b(kn[nt][3]);
            pv.x = f2b(vn[nt][0]); pv.y = f2b(vn[nt][1]); pv.z = f2b(vn[nt][2]); pv.w = f2b(vn[nt][3]);
            *(ushort4*)&kbuf[(nt * 16 + c) * 72 + m0 + quad * 4] = pk;
            *(ushort4*)&vbuf[(nt * 16 + c) * 72 + m0 + quad * 4] = pv;
        }
        __syncthreads();

        // ---- kv += k^T v : wave's d-band = 16w..16w+15, K = 64 toks ----
        short8 ka0 = *(const short8*)&kbuf[(m0 + c) * 72 + quad * 8];
        short8 ka1 = *(const short8*)&kbuf[(m0 + c) * 72 + 32 + quad * 8];
        #pragma unroll
        for (int nt = 0; nt < 4; ++nt) {
            short8 vb0 = *(const short8*)&vbuf[(nt * 16 + c) * 72 + quad * 8];
            short8 vb1 = *(const short8*)&vbuf[(nt * 16 + c) * 72 + 32 + quad * 8];
            akv[nt] = __builtin_amdgcn_mfma_f32_16x16x32_bf16(ka0, vb0, akv[nt], 0, 0, 0);
            akv[nt] = __builtin_amdgcn_mfma_f32_16x16x32_bf16(ka1, vb1, akv[nt], 0, 0, 0);
        }
        // next-iter loop-top __syncthreads orders kv reads vs. next writes
    }

    // kv D-layout: d = 16w + quad*4 + r, e = 16nt + c
    float* dst = kv_sum + (size_t)(b * H_ + h) * 4096;
    #pragma unroll
    for (int nt = 0; nt < 4; ++nt)
        #pragma unroll
        for (int r = 0; r < 4; ++r)
            atomicAdd(&dst[(size_t)(16 * w + quad * 4 + r) * 64 + nt * 16 + c], akv[nt][r]);
}

// ---------------------------------------------------------------------------
// Kernel 2: MT[b][h][j][d] = bf16( (1/N) * sum_e kv[b,h,d,e] * Wo[h*64+e, j] )
// Emitted TRANSPOSED + bf16 so k_out can load B-fragments directly.
// ---------------------------------------------------------------------------
__global__ __launch_bounds__(256) void k_m(
    const float* __restrict__ kv_sum,
    const float* __restrict__ Wo,
    unsigned short* __restrict__ MT)
{
    const int h = blockIdx.x, b = blockIdx.y;
    const int tid = threadIdx.x;
    __shared__ float kvs[64 * 65];
    __shared__ float wos[64 * 68];

    for (int i = tid; i < 4096; i += 256) {
        int d = i >> 6, e = i & 63;
        kvs[d * 65 + e] = kv_sum[(size_t)(b * H_ + h) * 4096 + i];
    }
    for (int i = tid; i < 1024; i += 256) {
        int dp = i >> 4, j4 = (i & 15) * 4;
        *(float4*)&wos[dp * 68 + j4] = *(const float4*)&Wo[(size_t)(h * 64 + dp) * 64 + j4];
    }
    __syncthreads();

    const int j0 = (tid & 15) * 4, d0 = (tid >> 4) * 4;
    float acc[4][4] = {{0.f}};
    #pragma unroll 4
    for (int dp = 0; dp < 64; ++dp) {
        float a_[4];
        #pragma unroll
        for (int i = 0; i < 4; ++i) a_[i] = kvs[(d0 + i) * 65 + dp];
        float4 w4 = *(const float4*)&wos[dp * 68 + j0];
        float w_[4] = {w4.x, w4.y, w4.z, w4.w};
        #pragma unroll
        for (int i = 0; i < 4; ++i)
            #pragma unroll
            for (int j = 0; j < 4; ++j)
                acc[i][j] += a_[i] * w_[j];
    }
    const float inv_n = 1.0f / (float)N_;
    unsigned short* dst = MT + (size_t)(b * H_ + h) * 4096;
    #pragma unroll
    for (int i = 0; i < 4; ++i)
        #pragma unroll
        for (int j = 0; j < 4; ++j)
            dst[(size_t)(j0 + j) * 64 + d0 + i] = f2b(acc[i][j] * inv_n);
}

// ---------------------------------------------------------------------------
// Kernel 3 (MFMA): out[b,n,:] = sum_h rope(x@Wq_h) @ M[b,h]   grid (N/64, B).
// Same fragment conventions as k_kv. B-operands (WqT, MT) loaded straight
// from global (L2-resident, pre-transposed bf16) -> no weight LDS, and the
// q round-trip (qbuf) is wave-local -> NO barriers in the head loop.
// ---------------------------------------------------------------------------
__global__ __launch_bounds__(256, 4) void k_out(
    const float* __restrict__ x,
    const float* __restrict__ pos,
    const unsigned short* __restrict__ WqT,
    const unsigned short* __restrict__ MT,
    float* __restrict__ out)
{
    const int b = blockIdx.y;
    const int n0 = blockIdx.x * 64;
    const int tid  = threadIdx.x;
    const int lane = tid & 63;
    const int w    = tid >> 6;
    const int c    = lane & 15;
    const int quad = lane >> 4;
    const int m0   = w * 16;          // wave's 16-token band

    __shared__ unsigned short xbuf[64 * 72];   // x tile bf16 [tok][kin]
    __shared__ unsigned short qbuf[64 * 72];   // q_rope bf16 [tok][feat] (wave-local bands)
    __shared__ float posb[64];

    // ---- stage x tile (bf16) + pos ----
    for (int i = tid; i < 1024; i += 256) {
        int r = i >> 4, c4 = (i & 15) * 4;
        float4 v = *(const float4*)&x[(size_t)(b * N_ + n0 + r) * 64 + c4];
        ushort4 u;
        u.x = f2b(v.x); u.y = f2b(v.y); u.z = f2b(v.z); u.w = f2b(v.w);
        *(ushort4*)&xbuf[r * 72 + c4] = u;
    }
    if (tid < 64) posb[tid] = pos[(size_t)b * N_ + n0 + tid] * 64.0f;
    __syncthreads();

    // ---- RoPE trig, head-independent: token = m0 + quad*4 + r ----
    const float invf_lo = exp2f(-0.4152410118609203f * (float)c);
    const float invf_hi = invf_lo * 0.01f;
    float csl[4], snl[4], csh[4], snh[4];
    #pragma unroll
    for (int r = 0; r < 4; ++r) {
        float tp = posb[m0 + quad * 4 + r];
        float al = tp * invf_lo, ah = tp * invf_hi;
        csl[r] = __cosf(al); snl[r] = __sinf(al);
        csh[r] = __cosf(ah); snh[r] = __sinf(ah);
    }

    // x A-fragments: constant across heads
    short8 a0 = *(const short8*)&xbuf[(m0 + c) * 72 + quad * 8];
    short8 a1 = *(const short8*)&xbuf[(m0 + c) * 72 + 32 + quad * 8];

    f32x4 oacc[4];
    #pragma unroll
    for (int nt = 0; nt < 4; ++nt) oacc[nt] = (f32x4){0.f, 0.f, 0.f, 0.f};

    #pragma unroll 1
    for (int h = 0; h < H_; ++h) {
        const unsigned short* wqh = WqT + (size_t)h * 4096;            // [feat][kin]
        const unsigned short* mth = MT + (size_t)(b * H_ + h) * 4096;  // [j][d]

        // ---- q proj: D[tok=quad*4+r][feat=nt*16+c] ----
        f32x4 aq[4];
        #pragma unroll
        for (int nt = 0; nt < 4; ++nt) {
            short8 b0 = *(const short8*)&wqh[(nt * 16 + c) * 64 + quad * 8];
            short8 b1 = *(const short8*)&wqh[(nt * 16 + c) * 64 + 32 + quad * 8];
            f32x4 z = {0.f, 0.f, 0.f, 0.f};
            z = __builtin_amdgcn_mfma_f32_16x16x32_bf16(a0, b0, z, 0, 0, 0);
            aq[nt] = __builtin_amdgcn_mfma_f32_16x16x32_bf16(a1, b1, z, 0, 0, 0);
        }

        // ---- RoPE(q): partner feat^32 = nt^2, same lane ----
        #pragma unroll
        for (int r = 0; r < 4; ++r) {
            float lo0 = aq[0][r], hi0 = aq[2][r];
            aq[0][r] = lo0 * csl[r] - hi0 * snl[r];
            aq[2][r] = hi0 * csl[r] + lo0 * snl[r];
            float lo1 = aq[1][r], hi1 = aq[3][r];
            aq[1][r] = lo1 * csh[r] - hi1 * snh[r];
            aq[3][r] = hi1 * csh[r] + lo1 * snh[r];
        }

        // ---- pack q_rope -> qbuf [tok][feat]; wave-local rows, no barrier ----
        #pragma unroll
        for (int nt = 0; nt < 4; ++nt)
            #pragma unroll
            for (int r = 0; r < 4; ++r)
                qbuf[(m0 + quad * 4 + r) * 72 + nt * 16 + c] = f2b(aq[nt][r]);

        // ---- out += q_rope @ M_h : D[tok][j=nt*16+c] ----
        short8 qa0 = *(const short8*)&qbuf[(m0 + c) * 72 + quad * 8];
        short8 qa1 = *(const short8*)&qbuf[(m0 + c) * 72 + 32 + quad * 8];
        #pragma unroll
        for (int nt = 0; nt < 4; ++nt) {
            short8 mb0 = *(const short8*)&mth[(nt * 16 + c) * 64 + quad * 8];
            short8 mb1 = *(const short8*)&mth[(nt * 16 + c) * 64 + 32 + quad * 8];
            oacc[nt] = __builtin_amdgcn_mfma_f32_16x16x32_bf16(qa0, mb0, oacc[nt], 0, 0, 0);
            oacc[nt] = __builtin_amdgcn_mfma_f32_16x16x32_bf16(qa1, mb1, oacc[nt], 0, 0, 0);
        }
    }

    // ---- store: out[tok][j], tok = m0+quad*4+r, j = nt*16+c ----
    #pragma unroll
    for (int nt = 0; nt < 4; ++nt)
        #pragma unroll
        for (int r = 0; r < 4; ++r)
            out[(size_t)(b * N_ + n0 + m0 + quad * 4 + r) * 64 + nt * 16 + c] = oacc[nt][r];
}

// ---------------------------------------------------------------------------
extern "C" void kernel_launch(void* const* d_in, const int* in_sizes, int n_in,
                              void* d_out, int out_size, void* d_ws, size_t ws_size,
                              hipStream_t stream)
{
    const float* x   = (const float*)d_in[0];
    const float* pos = (const float*)d_in[1];
    const float* Wq  = (const float*)d_in[2];
    const float* Wk  = (const float*)d_in[3];
    const float* Wv  = (const float*)d_in[4];
    const float* Wo  = (const float*)d_in[5];
    float* out = (float*)d_out;

    char* ws = (char*)d_ws;
    float* kv_sum      = (float*)ws;                            // 512 KB
    unsigned short* MT  = (unsigned short*)(ws + 524288);       // 256 KB
    unsigned short* WqT = (unsigned short*)(ws + 524288 + 262144); // 64 KB

    k_init<<<dim3(512), 256, 0, stream>>>(kv_sum);
    k_wqt <<<dim3(128), 256, 0, stream>>>(Wq, WqT);
    k_kv  <<<dim3(NCHUNK, H_, B_), 256, 0, stream>>>(x, pos, Wk, Wv, kv_sum);
    k_m   <<<dim3(H_, B_), 256, 0, stream>>>(kv_sum, Wo, MT);
    k_out <<<dim3(NTILES, B_), 256, 0, stream>>>(x, pos, WqT, MT, out);
}

// Round 2
// 155.636 us; speedup vs baseline: 1.7084x; 1.2887x over previous
//
#include <hip/hip_runtime.h>

#define B_ 4
#define N_ 16384
#define D_ 64
#define H_ 8
#define E_ 512
#define NCHUNK 24
#define NTILES (N_ / 64)

typedef __attribute__((ext_vector_type(8))) short short8;
typedef __attribute__((ext_vector_type(4))) float f32x4;

// f32 -> bf16 (RNE)
__device__ __forceinline__ unsigned short f2b(float f) {
    unsigned u = __float_as_uint(f);
    return (unsigned short)((u + 0x7fffu + ((u >> 16) & 1u)) >> 16);
}

// ---------------------------------------------------------------------------
// k_init: zero kv_sum (B*H*4096 f32)
// ---------------------------------------------------------------------------
__global__ __launch_bounds__(256) void k_init(float* kv_sum)
{
    kv_sum[blockIdx.x * 256 + threadIdx.x] = 0.f;
}

// ---------------------------------------------------------------------------
// k_wqt: pack Wq into per-head B-fragment blobs (bf16).
// Blob layout per head: [fr=nt*2+half][lane][e] u16 (8*64*8 = 4096 u16 = 8KB).
// Element = Wq[kin][h*64+feat],  feat = nt*16 + (lane&15),
//           kin = (lane>>4)*8 + half*32 + e.
// Each lane's 16B frag load in k_out is then lane-linear (coalesced 1KB/wave).
// ---------------------------------------------------------------------------
__global__ __launch_bounds__(256) void k_wqt(const float* __restrict__ Wq,
                                             unsigned short* __restrict__ WqB)
{
    int id = blockIdx.x * 256 + threadIdx.x;   // 32768 = 64*512 (all of Wq)
    int kin = id >> 9, f = id & 511;
    int h = f >> 6, feat = f & 63;
    int nt = feat >> 4, cc = feat & 15;
    int half = kin >> 5, qd = (kin >> 3) & 3, e = kin & 7;
    WqB[(size_t)h * 4096 + (((nt * 2 + half) * 64 + qd * 16 + cc) * 8) + e]
        = f2b(Wq[id]);
}

// ---------------------------------------------------------------------------
// Kernel 1 (MFMA): k,v projection + LN + RoPE(k) + kv accumulation.
// grid (NCHUNK, H, B), 256 thr = 4 waves. mfma_f32_16x16x32_bf16.
// Layouts (verified): A[m=lane&15][k=quad*8+j]; D col=lane&15,row=quad*4+reg.
// LDS rows stride 72 u16 = 144 B (16B-aligned for b128 frag loads).
// T14 pipeline: next tile's x/pos issued into regs right after loop-top
// barrier; committed to xbuf at the next loop top (HBM latency hidden under
// proj/LN/RoPE/kv compute). Hazard: xbuf reads (a0/a1) are pre-2nd-barrier,
// commit is post-loop-top-barrier -> safe, 2 barriers/tile unchanged.
// ---------------------------------------------------------------------------
__global__ __launch_bounds__(256, 3) void k_kv(
    const float* __restrict__ x,
    const float* __restrict__ pos,
    const float* __restrict__ Wk,
    const float* __restrict__ Wv,
    float* __restrict__ kv_sum)
{
    const int b = blockIdx.z, h = blockIdx.y, chunk = blockIdx.x;
    const int tid  = threadIdx.x;
    const int lane = tid & 63;
    const int w    = tid >> 6;        // wave id 0..3
    const int c    = lane & 15;
    const int quad = lane >> 4;
    const int m0   = w * 16;          // wave's 16-row band (tokens in proj, feats in kv)

    __shared__ unsigned short xbuf[64 * 72];   // x tile bf16 [tok][kin]
    __shared__ unsigned short wkb[64 * 72];    // Wk^T bf16 [feat][kin]
    __shared__ unsigned short wvb[64 * 72];    // Wv^T bf16 [feat][kin]
    __shared__ unsigned short kbuf[64 * 72];   // k bf16 [feat][tok]
    __shared__ unsigned short vbuf[64 * 72];   // v bf16 [feat][tok]
    __shared__ float posb[64];

    // ---- prologue: issue first tile's x/pos loads (regs) ----
    float4 px[4];
    float ppos = 0.f;
    {
        const int n0 = chunk * 64;
        #pragma unroll
        for (int j = 0; j < 4; ++j) {
            int i = tid + j * 256, r = i >> 4, c4 = (i & 15) * 4;
            px[j] = *(const float4*)&x[(size_t)(b * N_ + n0 + r) * 64 + c4];
        }
        if (tid < 64) ppos = pos[(size_t)b * N_ + n0 + tid];
    }

    // Stage W transposed (once per block; overlaps first x load latency)
    for (int i = tid; i < 1024; i += 256) {
        int kin = i >> 4, c4 = (i & 15) * 4;
        float4 wk4 = *(const float4*)&Wk[(size_t)kin * E_ + h * 64 + c4];
        float4 wv4 = *(const float4*)&Wv[(size_t)kin * E_ + h * 64 + c4];
        wkb[(c4 + 0) * 72 + kin] = f2b(wk4.x);
        wkb[(c4 + 1) * 72 + kin] = f2b(wk4.y);
        wkb[(c4 + 2) * 72 + kin] = f2b(wk4.z);
        wkb[(c4 + 3) * 72 + kin] = f2b(wk4.w);
        wvb[(c4 + 0) * 72 + kin] = f2b(wv4.x);
        wvb[(c4 + 1) * 72 + kin] = f2b(wv4.y);
        wvb[(c4 + 2) * 72 + kin] = f2b(wv4.z);
        wvb[(c4 + 3) * 72 + kin] = f2b(wv4.w);
    }

    const float invf_lo = exp2f(-0.4152410118609203f * (float)c);  // 10000^(-c/32)
    const float invf_hi = invf_lo * 0.01f;                          // 10000^(-(16+c)/32)

    f32x4 akv[4];
    #pragma unroll
    for (int nt = 0; nt < 4; ++nt) akv[nt] = (f32x4){0.f, 0.f, 0.f, 0.f};

    for (int tile = chunk; tile < NTILES; tile += NCHUNK) {
        // ---- commit staged regs -> xbuf / posb ----
        #pragma unroll
        for (int j = 0; j < 4; ++j) {
            int i = tid + j * 256, r = i >> 4, c4 = (i & 15) * 4;
            ushort4 u;
            u.x = f2b(px[j].x); u.y = f2b(px[j].y); u.z = f2b(px[j].z); u.w = f2b(px[j].w);
            *(ushort4*)&xbuf[r * 72 + c4] = u;
        }
        if (tid < 64) posb[tid] = ppos * 64.0f;
        __syncthreads();

        // ---- issue next tile's loads (latency hidden under this tile) ----
        const int tn = tile + NCHUNK;
        if (tn < NTILES) {
            const int nn = tn * 64;
            #pragma unroll
            for (int j = 0; j < 4; ++j) {
                int i = tid + j * 256, r = i >> 4, c4 = (i & 15) * 4;
                px[j] = *(const float4*)&x[(size_t)(b * N_ + nn + r) * 64 + c4];
            }
            if (tid < 64) ppos = pos[(size_t)b * N_ + nn + tid];
        }

        // ---- proj: tokens m0..m0+15 x feats 0..63, K=64 (2 steps) ----
        short8 a0 = *(const short8*)&xbuf[(m0 + c) * 72 + quad * 8];
        short8 a1 = *(const short8*)&xbuf[(m0 + c) * 72 + 32 + quad * 8];
        f32x4 ak[4], av[4];
        #pragma unroll
        for (int nt = 0; nt < 4; ++nt) {
            short8 bk0 = *(const short8*)&wkb[(nt * 16 + c) * 72 + quad * 8];
            short8 bk1 = *(const short8*)&wkb[(nt * 16 + c) * 72 + 32 + quad * 8];
            f32x4 z = {0.f, 0.f, 0.f, 0.f};
            z = __builtin_amdgcn_mfma_f32_16x16x32_bf16(a0, bk0, z, 0, 0, 0);
            ak[nt] = __builtin_amdgcn_mfma_f32_16x16x32_bf16(a1, bk1, z, 0, 0, 0);
            short8 bv0 = *(const short8*)&wvb[(nt * 16 + c) * 72 + quad * 8];
            short8 bv1 = *(const short8*)&wvb[(nt * 16 + c) * 72 + 32 + quad * 8];
            f32x4 y = {0.f, 0.f, 0.f, 0.f};
            y = __builtin_amdgcn_mfma_f32_16x16x32_bf16(a0, bv0, y, 0, 0, 0);
            av[nt] = __builtin_amdgcn_mfma_f32_16x16x32_bf16(a1, bv1, y, 0, 0, 0);
        }

        // ---- LN per token (row = quad*4+r; feats spread over nt x 16 lanes) ----
        float kn[4][4], vn[4][4];   // [nt][r]
        #pragma unroll
        for (int r = 0; r < 4; ++r) {
            float sk  = ak[0][r] + ak[1][r] + ak[2][r] + ak[3][r];
            float sk2 = ak[0][r]*ak[0][r] + ak[1][r]*ak[1][r] + ak[2][r]*ak[2][r] + ak[3][r]*ak[3][r];
            float sv  = av[0][r] + av[1][r] + av[2][r] + av[3][r];
            float sv2 = av[0][r]*av[0][r] + av[1][r]*av[1][r] + av[2][r]*av[2][r] + av[3][r]*av[3][r];
            #pragma unroll
            for (int msk = 1; msk < 16; msk <<= 1) {
                sk  += __shfl_xor(sk,  msk, 64);
                sk2 += __shfl_xor(sk2, msk, 64);
                sv  += __shfl_xor(sv,  msk, 64);
                sv2 += __shfl_xor(sv2, msk, 64);
            }
            float mk = sk * (1.0f / 64.0f);
            float rk = rsqrtf(sk2 * (1.0f / 64.0f) - mk * mk + 1e-5f);
            float mv = sv * (1.0f / 64.0f);
            float rv = rsqrtf(sv2 * (1.0f / 64.0f) - mv * mv + 1e-5f);
            #pragma unroll
            for (int nt = 0; nt < 4; ++nt) {
                kn[nt][r] = (ak[nt][r] - mk) * rk;
                vn[nt][r] = (av[nt][r] - mv) * rv;
            }
        }

        // ---- RoPE(k): feat=16nt+c; partner feat^32 = tile nt^2, same lane ----
        #pragma unroll
        for (int r = 0; r < 4; ++r) {
            float tp = posb[m0 + quad * 4 + r];
            float al = tp * invf_lo, ah = tp * invf_hi;
            float cl = __cosf(al), sl = __sinf(al);
            float ch = __cosf(ah), sh = __sinf(ah);
            float lo0 = kn[0][r], hi0 = kn[2][r];
            kn[0][r] = lo0 * cl - hi0 * sl;
            kn[2][r] = hi0 * cl + lo0 * sl;
            float lo1 = kn[1][r], hi1 = kn[3][r];
            kn[1][r] = lo1 * ch - hi1 * sh;
            kn[3][r] = hi1 * ch + lo1 * sh;
        }

        // ---- pack bf16, store transposed [feat][tok] ----
        #pragma unroll
        for (int nt = 0; nt < 4; ++nt) {
            ushort4 pk, pv;
            pk.x = f2b(kn[nt][0]); pk.y = f2b(kn[nt][1]); pk.z = f2b(kn[nt][2]); pk.w = f2b(kn[nt][3]);
            pv.x = f2b(vn[nt][0]); pv.y = f2b(vn[nt][1]); pv.z = f2b(vn[nt][2]); pv.w = f2b(vn[nt][3]);
            *(ushort4*)&kbuf[(nt * 16 + c) * 72 + m0 + quad * 4] = pk;
            *(ushort4*)&vbuf[(nt * 16 + c) * 72 + m0 + quad * 4] = pv;
        }
        __syncthreads();

        // ---- kv += k^T v : wave's d-band = 16w..16w+15, K = 64 toks ----
        short8 ka0 = *(const short8*)&kbuf[(m0 + c) * 72 + quad * 8];
        short8 ka1 = *(const short8*)&kbuf[(m0 + c) * 72 + 32 + quad * 8];
        #pragma unroll
        for (int nt = 0; nt < 4; ++nt) {
            short8 vb0 = *(const short8*)&vbuf[(nt * 16 + c) * 72 + quad * 8];
            short8 vb1 = *(const short8*)&vbuf[(nt * 16 + c) * 72 + 32 + quad * 8];
            akv[nt] = __builtin_amdgcn_mfma_f32_16x16x32_bf16(ka0, vb0, akv[nt], 0, 0, 0);
            akv[nt] = __builtin_amdgcn_mfma_f32_16x16x32_bf16(ka1, vb1, akv[nt], 0, 0, 0);
        }
        // next-iter loop-top __syncthreads orders kv reads vs. next xbuf writes
    }

    // kv D-layout: d = 16w + quad*4 + r, e = 16nt + c
    float* dst = kv_sum + (size_t)(b * H_ + h) * 4096;
    #pragma unroll
    for (int nt = 0; nt < 4; ++nt)
        #pragma unroll
        for (int r = 0; r < 4; ++r)
            atomicAdd(&dst[(size_t)(16 * w + quad * 4 + r) * 64 + nt * 16 + c], akv[nt][r]);
}

// ---------------------------------------------------------------------------
// Kernel 2: M = (1/N) kv @ Wo_h, emitted as bf16 B-fragment blobs (same blob
// layout as k_wqt): blob rows = j (out col), cols = d (contraction index).
// ---------------------------------------------------------------------------
__global__ __launch_bounds__(256) void k_m(
    const float* __restrict__ kv_sum,
    const float* __restrict__ Wo,
    unsigned short* __restrict__ MTB)
{
    const int h = blockIdx.x, b = blockIdx.y;
    const int tid = threadIdx.x;
    __shared__ float kvs[64 * 65];
    __shared__ float wos[64 * 68];

    for (int i = tid; i < 4096; i += 256) {
        int d = i >> 6, e = i & 63;
        kvs[d * 65 + e] = kv_sum[(size_t)(b * H_ + h) * 4096 + i];
    }
    for (int i = tid; i < 1024; i += 256) {
        int dp = i >> 4, j4 = (i & 15) * 4;
        *(float4*)&wos[dp * 68 + j4] = *(const float4*)&Wo[(size_t)(h * 64 + dp) * 64 + j4];
    }
    __syncthreads();

    const int j0 = (tid & 15) * 4, d0 = (tid >> 4) * 4;
    float acc[4][4] = {{0.f}};
    #pragma unroll 4
    for (int dp = 0; dp < 64; ++dp) {
        float a_[4];
        #pragma unroll
        for (int i = 0; i < 4; ++i) a_[i] = kvs[(d0 + i) * 65 + dp];
        float4 w4 = *(const float4*)&wos[dp * 68 + j0];
        float w_[4] = {w4.x, w4.y, w4.z, w4.w};
        #pragma unroll
        for (int i = 0; i < 4; ++i)
            #pragma unroll
            for (int j = 0; j < 4; ++j)
                acc[i][j] += a_[i] * w_[j];
    }
    const float inv_n = 1.0f / (float)N_;
    unsigned short* dst = MTB + (size_t)(b * H_ + h) * 4096;
    #pragma unroll
    for (int i = 0; i < 4; ++i)
        #pragma unroll
        for (int j = 0; j < 4; ++j) {
            int d = d0 + i, jj = j0 + j;
            int nt = jj >> 4, cc = jj & 15;
            int half = d >> 5, qd = (d >> 3) & 3, e = d & 7;
            dst[(((nt * 2 + half) * 64 + qd * 16 + cc) * 8) + e] = f2b(acc[i][j] * inv_n);
        }
}

// ---------------------------------------------------------------------------
// Kernel 3 (MFMA): out[b,n,:] = sum_h rope(x@Wq_h) @ M[b,h]   grid (N/64, B).
// B-operands come from fragment blobs: each lane's frag load is lane-linear
// 16B (coalesced 1KB/wave, L2-resident). Software-pipelined head loop:
//   - W(h+1) issued right after q-proj consumes W(h)  (covered by rope+PV)
//   - Mt(h+1) issued right after PV consumes Mt(h)    (covered by next q-proj)
//   - h=0 frags issued before x staging (covered by staging+barrier)
// Head loop stays barrier-free (qbuf rows are wave-local).
// ---------------------------------------------------------------------------
__global__ __launch_bounds__(256, 3) void k_out(
    const float* __restrict__ x,
    const float* __restrict__ pos,
    const unsigned short* __restrict__ WqB,
    const unsigned short* __restrict__ MTB,
    float* __restrict__ out)
{
    const int b = blockIdx.y;
    const int n0 = blockIdx.x * 64;
    const int tid  = threadIdx.x;
    const int lane = tid & 63;
    const int w    = tid >> 6;
    const int c    = lane & 15;
    const int quad = lane >> 4;
    const int m0   = w * 16;          // wave's 16-token band

    __shared__ unsigned short xbuf[64 * 72];   // x tile bf16 [tok][kin]
    __shared__ unsigned short qbuf[64 * 72];   // q_rope bf16 [tok][feat] (wave-local bands)
    __shared__ float posb[64];

    const unsigned short* wq0 = WqB + (size_t)lane * 8;
    const unsigned short* mt0 = MTB + (size_t)(b * H_) * 4096 + (size_t)lane * 8;

    // ---- issue h=0 fragment loads (latency hidden under x staging) ----
    short8 W[8], Mt[8];
    #pragma unroll
    for (int fr = 0; fr < 8; ++fr) W[fr]  = *(const short8*)&wq0[fr * 512];
    #pragma unroll
    for (int fr = 0; fr < 8; ++fr) Mt[fr] = *(const short8*)&mt0[fr * 512];

    // ---- stage x tile (bf16) + pos ----
    for (int i = tid; i < 1024; i += 256) {
        int r = i >> 4, c4 = (i & 15) * 4;
        float4 v = *(const float4*)&x[(size_t)(b * N_ + n0 + r) * 64 + c4];
        ushort4 u;
        u.x = f2b(v.x); u.y = f2b(v.y); u.z = f2b(v.z); u.w = f2b(v.w);
        *(ushort4*)&xbuf[r * 72 + c4] = u;
    }
    if (tid < 64) posb[tid] = pos[(size_t)b * N_ + n0 + tid] * 64.0f;
    __syncthreads();

    // ---- RoPE trig, head-independent: token = m0 + quad*4 + r ----
    const float invf_lo = exp2f(-0.4152410118609203f * (float)c);
    const float invf_hi = invf_lo * 0.01f;
    float csl[4], snl[4], csh[4], snh[4];
    #pragma unroll
    for (int r = 0; r < 4; ++r) {
        float tp = posb[m0 + quad * 4 + r];
        float al = tp * invf_lo, ah = tp * invf_hi;
        csl[r] = __cosf(al); snl[r] = __sinf(al);
        csh[r] = __cosf(ah); snh[r] = __sinf(ah);
    }

    // x A-fragments: constant across heads
    short8 a0 = *(const short8*)&xbuf[(m0 + c) * 72 + quad * 8];
    short8 a1 = *(const short8*)&xbuf[(m0 + c) * 72 + 32 + quad * 8];

    f32x4 oacc[4];
    #pragma unroll
    for (int nt = 0; nt < 4; ++nt) oacc[nt] = (f32x4){0.f, 0.f, 0.f, 0.f};

    #pragma unroll
    for (int h = 0; h < H_; ++h) {
        // ---- q proj: D[tok=quad*4+r][feat=nt*16+c] (consumes W) ----
        f32x4 aq[4];
        #pragma unroll
        for (int nt = 0; nt < 4; ++nt) {
            f32x4 z = {0.f, 0.f, 0.f, 0.f};
            z = __builtin_amdgcn_mfma_f32_16x16x32_bf16(a0, W[nt * 2 + 0], z, 0, 0, 0);
            aq[nt] = __builtin_amdgcn_mfma_f32_16x16x32_bf16(a1, W[nt * 2 + 1], z, 0, 0, 0);
        }

        // ---- prefetch W for h+1 (W regs now dead; covered by rope+PV) ----
        if (h < H_ - 1) {
            #pragma unroll
            for (int fr = 0; fr < 8; ++fr)
                W[fr] = *(const short8*)&wq0[(size_t)(h + 1) * 4096 + fr * 512];
        }

        // ---- RoPE(q): partner feat^32 = tile nt^2, same lane ----
        #pragma unroll
        for (int r = 0; r < 4; ++r) {
            float lo0 = aq[0][r], hi0 = aq[2][r];
            aq[0][r] = lo0 * csl[r] - hi0 * snl[r];
            aq[2][r] = hi0 * csl[r] + lo0 * snl[r];
            float lo1 = aq[1][r], hi1 = aq[3][r];
            aq[1][r] = lo1 * csh[r] - hi1 * snh[r];
            aq[3][r] = hi1 * csh[r] + lo1 * snh[r];
        }

        // ---- pack q_rope -> qbuf [tok][feat]; wave-local rows, no barrier ----
        #pragma unroll
        for (int nt = 0; nt < 4; ++nt)
            #pragma unroll
            for (int r = 0; r < 4; ++r)
                qbuf[(m0 + quad * 4 + r) * 72 + nt * 16 + c] = f2b(aq[nt][r]);

        // ---- out += q_rope @ M_h : D[tok][j=nt*16+c] (consumes Mt) ----
        short8 qa0 = *(const short8*)&qbuf[(m0 + c) * 72 + quad * 8];
        short8 qa1 = *(const short8*)&qbuf[(m0 + c) * 72 + 32 + quad * 8];
        #pragma unroll
        for (int nt = 0; nt < 4; ++nt) {
            oacc[nt] = __builtin_amdgcn_mfma_f32_16x16x32_bf16(qa0, Mt[nt * 2 + 0], oacc[nt], 0, 0, 0);
            oacc[nt] = __builtin_amdgcn_mfma_f32_16x16x32_bf16(qa1, Mt[nt * 2 + 1], oacc[nt], 0, 0, 0);
        }

        // ---- prefetch Mt for h+1 (Mt regs now dead; covered by next q-proj) ----
        if (h < H_ - 1) {
            #pragma unroll
            for (int fr = 0; fr < 8; ++fr)
                Mt[fr] = *(const short8*)&mt0[(size_t)(h + 1) * 4096 + fr * 512];
        }
    }

    // ---- store: out[tok][j], tok = m0+quad*4+r, j = nt*16+c ----
    #pragma unroll
    for (int nt = 0; nt < 4; ++nt)
        #pragma unroll
        for (int r = 0; r < 4; ++r)
            out[(size_t)(b * N_ + n0 + m0 + quad * 4 + r) * 64 + nt * 16 + c] = oacc[nt][r];
}

// ---------------------------------------------------------------------------
extern "C" void kernel_launch(void* const* d_in, const int* in_sizes, int n_in,
                              void* d_out, int out_size, void* d_ws, size_t ws_size,
                              hipStream_t stream)
{
    const float* x   = (const float*)d_in[0];
    const float* pos = (const float*)d_in[1];
    const float* Wq  = (const float*)d_in[2];
    const float* Wk  = (const float*)d_in[3];
    const float* Wv  = (const float*)d_in[4];
    const float* Wo  = (const float*)d_in[5];
    float* out = (float*)d_out;

    char* ws = (char*)d_ws;
    float* kv_sum       = (float*)ws;                              // 512 KB
    unsigned short* MTB = (unsigned short*)(ws + 524288);          // 256 KB
    unsigned short* WqB = (unsigned short*)(ws + 524288 + 262144); // 64 KB

    k_init<<<dim3(512), 256, 0, stream>>>(kv_sum);
    k_wqt <<<dim3(128), 256, 0, stream>>>(Wq, WqB);
    k_kv  <<<dim3(NCHUNK, H_, B_), 256, 0, stream>>>(x, pos, Wk, Wv, kv_sum);
    k_m   <<<dim3(H_, B_), 256, 0, stream>>>(kv_sum, Wo, MTB);
    k_out <<<dim3(NTILES, B_), 256, 0, stream>>>(x, pos, WqB, MTB, out);
}